// Round 1
// baseline (1077.538 us; speedup 1.0000x reference)
//
#include <hip/hip_runtime.h>
#include <stdint.h>

#define NN 100000
#define EE 600000
#define DD 128

typedef _Float16 half8 __attribute__((ext_vector_type(8)));
typedef float f32x4 __attribute__((ext_vector_type(4)));

// ---------------------------------------------------------------------------
// Prep: split W1/W2 into f16 hi/lo pairs, rearranged into MFMA B-fragment
// linear order: frag f = (kt*8 + nt), element [f*64 + lane]*8 + j,
// where k = kt*32 + (lane>>4)*8 + j, d = nt*16 + (lane&15).
// ---------------------------------------------------------------------------
__global__ __launch_bounds__(256)
void prep_weights(const float* __restrict__ W1, const float* __restrict__ W2,
                  _Float16* __restrict__ w1hi, _Float16* __restrict__ w1lo,
                  _Float16* __restrict__ w2hi, _Float16* __restrict__ w2lo)
{
    int t = blockIdx.x * 256 + threadIdx.x;
    if (t >= 2 * DD * DD) return;
    int which = t >> 14;           // 0 -> W1, 1 -> W2
    int idx = t & (DD * DD - 1);
    int k = idx >> 7;
    int d = idx & 127;
    float wv = (which ? W2 : W1)[k * DD + d];
    _Float16 hi = (_Float16)wv;
    _Float16 lo = (_Float16)(wv - (float)hi);
    int kt = k >> 5, kr = k & 31;
    int grp = kr >> 3, j = kr & 7;
    int nt = d >> 4, cc = d & 15;
    int lane = grp * 16 + cc;
    int off = ((kt * 8 + nt) * 64 + lane) * 8 + j;
    if (which) { w2hi[off] = hi; w2lo[off] = lo; }
    else       { w1hi[off] = hi; w1lo[off] = lo; }
}

// ---------------------------------------------------------------------------
// Edge phase: msg = relu(x[src] + edge_attr@W_e + b_e); atomicAdd into agg[dst].
// 32 threads per edge, one float4 of the 128-wide feature each.
// W_e column slice (6x4) + b_e slice live in registers, amortized by
// grid-stride over edges (thread keeps the same feature chunk c).
// ---------------------------------------------------------------------------
__global__ __launch_bounds__(256)
void edge_kernel(const float* __restrict__ x, const int* __restrict__ ei,
                 const float* __restrict__ ea, const float* __restrict__ We,
                 const float* __restrict__ be, float* agg)
{
    int tid = blockIdx.x * 256 + threadIdx.x;
    int c = tid & 31;
    int d0 = c * 4;
    float4 w0 = *(const float4*)(We + 0 * DD + d0);
    float4 w1 = *(const float4*)(We + 1 * DD + d0);
    float4 w2 = *(const float4*)(We + 2 * DD + d0);
    float4 w3 = *(const float4*)(We + 3 * DD + d0);
    float4 w4 = *(const float4*)(We + 4 * DD + d0);
    float4 w5 = *(const float4*)(We + 5 * DD + d0);
    float4 bb = *(const float4*)(be + d0);
    int estride = (gridDim.x * 256) >> 5;
    for (int e = tid >> 5; e < EE; e += estride) {
        int src = ei[e];
        int dst = ei[EE + e];
        const float2* eap = (const float2*)(ea + e * 6);
        float2 e01 = eap[0];
        float2 e23 = eap[1];
        float2 e45 = eap[2];
        float4 xj = *(const float4*)(x + (size_t)src * DD + d0);
        float mx = xj.x + bb.x + e01.x*w0.x + e01.y*w1.x + e23.x*w2.x + e23.y*w3.x + e45.x*w4.x + e45.y*w5.x;
        float my = xj.y + bb.y + e01.x*w0.y + e01.y*w1.y + e23.x*w2.y + e23.y*w3.y + e45.x*w4.y + e45.y*w5.y;
        float mz = xj.z + bb.z + e01.x*w0.z + e01.y*w1.z + e23.x*w2.z + e23.y*w3.z + e45.x*w4.z + e45.y*w5.z;
        float mw = xj.w + bb.w + e01.x*w0.w + e01.y*w1.w + e23.x*w2.w + e23.y*w3.w + e45.x*w4.w + e45.y*w5.w;
        float* ap = agg + (size_t)dst * DD + d0;
        atomicAdd(ap + 0, fmaxf(mx, 0.f));
        atomicAdd(ap + 1, fmaxf(my, 0.f));
        atomicAdd(ap + 2, fmaxf(mz, 0.f));
        atomicAdd(ap + 3, fmaxf(mw, 0.f));
    }
}

// ---------------------------------------------------------------------------
// Node phase: h0 = (1+eps)*x + agg; h1 = relu(h0@W1+b1); h2 = h1@W2+b2;
// out = relu(LN(h2)*gamma+beta).  One wave = 16 rows x 128 cols, MFMA
// f32_16x16x32_f16 with 2-term f16 split (3 MFMAs per k/n tile).
// agg == out (in-place, row-local).
// ---------------------------------------------------------------------------
__global__ __launch_bounds__(256)
void node_kernel(const float* __restrict__ x, const float* agg,
                 const _Float16* __restrict__ w1hi, const _Float16* __restrict__ w1lo,
                 const _Float16* __restrict__ w2hi, const _Float16* __restrict__ w2lo,
                 const float* __restrict__ b1, const float* __restrict__ b2,
                 const float* __restrict__ gamma, const float* __restrict__ beta,
                 const float* __restrict__ epsp, float* out)
{
    __shared__ uint32_t h1buf[4][16 * 128];  // 32 KiB, 8 KiB per wave
    const int wv = threadIdx.x >> 6;
    const int l  = threadIdx.x & 63;
    const int lm = l & 15;
    const int lg = l >> 4;
    const int r0 = blockIdx.x * 64 + wv * 16;
    const float scale = 1.0f + epsp[0];

    // ---- GEMM1 A fragments straight from global (row = lm, k = kt*32+lg*8+j)
    int arow = r0 + lm;
    if (arow >= NN) arow = NN - 1;   // OOB waves compute garbage, stores predicated
    half8 ahi[4], alo[4];
#pragma unroll
    for (int kt = 0; kt < 4; ++kt) {
        const int kb = kt * 32 + lg * 8;
        const float4* xp = (const float4*)(x   + (size_t)arow * DD + kb);
        const float4* ap = (const float4*)(agg + (size_t)arow * DD + kb);
        float4 x0 = xp[0], x1 = xp[1];
        float4 a0 = ap[0], a1 = ap[1];
        float v[8] = { x0.x*scale + a0.x, x0.y*scale + a0.y, x0.z*scale + a0.z, x0.w*scale + a0.w,
                       x1.x*scale + a1.x, x1.y*scale + a1.y, x1.z*scale + a1.z, x1.w*scale + a1.w };
#pragma unroll
        for (int j = 0; j < 8; ++j) {
            _Float16 h = (_Float16)v[j];
            ahi[kt][j] = h;
            alo[kt][j] = (_Float16)(v[j] - (float)h);
        }
    }

    f32x4 acc[8];
#pragma unroll
    for (int nt = 0; nt < 8; ++nt) { acc[nt][0]=0.f; acc[nt][1]=0.f; acc[nt][2]=0.f; acc[nt][3]=0.f; }

#pragma unroll
    for (int kt = 0; kt < 4; ++kt) {
#pragma unroll
        for (int nt = 0; nt < 8; ++nt) {
            const int f = ((kt * 8 + nt) * 64 + l) * 8;
            half8 bh = *(const half8*)(w1hi + f);
            half8 bl = *(const half8*)(w1lo + f);
            acc[nt] = __builtin_amdgcn_mfma_f32_16x16x32_f16(alo[kt], bh, acc[nt], 0, 0, 0);
            acc[nt] = __builtin_amdgcn_mfma_f32_16x16x32_f16(ahi[kt], bl, acc[nt], 0, 0, 0);
            acc[nt] = __builtin_amdgcn_mfma_f32_16x16x32_f16(ahi[kt], bh, acc[nt], 0, 0, 0);
        }
    }

    // ---- epilogue 1: relu(+b1), f16-split, pack (hi|lo<<16), LDS XOR-swizzled
    uint32_t* hb = h1buf[wv];
#pragma unroll
    for (int nt = 0; nt < 8; ++nt) {
        const int col = nt * 16 + lm;
        const float bias = b1[col];
#pragma unroll
        for (int q = 0; q < 4; ++q) {
            const int row = lg * 4 + q;
            float v1 = fmaxf(acc[nt][q] + bias, 0.f);
            _Float16 h = (_Float16)v1;
            _Float16 lo2 = (_Float16)(v1 - (float)h);
            uint32_t pk = (uint32_t)__builtin_bit_cast(uint16_t, h)
                        | ((uint32_t)__builtin_bit_cast(uint16_t, lo2) << 16);
            hb[row * 128 + (col ^ ((row & 7) << 2))] = pk;
        }
    }
    __syncthreads();

    // ---- GEMM2 A fragments from LDS (same swizzle on read)
    half8 ahi2[4], alo2[4];
    {
        const int s = (lm & 7) << 2;
        const uint32_t* rowp = hb + lm * 128;
#pragma unroll
        for (int kt = 0; kt < 4; ++kt) {
            const int kb = kt * 32 + lg * 8;
            uint4 t0 = *(const uint4*)(rowp + ((kb    ) ^ s));
            uint4 t1 = *(const uint4*)(rowp + ((kb + 4) ^ s));
            uint32_t u[8] = {t0.x, t0.y, t0.z, t0.w, t1.x, t1.y, t1.z, t1.w};
#pragma unroll
            for (int j = 0; j < 8; ++j) {
                ahi2[kt][j] = __builtin_bit_cast(_Float16, (uint16_t)(u[j] & 0xffffu));
                alo2[kt][j] = __builtin_bit_cast(_Float16, (uint16_t)(u[j] >> 16));
            }
        }
    }

    f32x4 acc2[8];
#pragma unroll
    for (int nt = 0; nt < 8; ++nt) { acc2[nt][0]=0.f; acc2[nt][1]=0.f; acc2[nt][2]=0.f; acc2[nt][3]=0.f; }
#pragma unroll
    for (int kt = 0; kt < 4; ++kt) {
#pragma unroll
        for (int nt = 0; nt < 8; ++nt) {
            const int f = ((kt * 8 + nt) * 64 + l) * 8;
            half8 bh = *(const half8*)(w2hi + f);
            half8 bl = *(const half8*)(w2lo + f);
            acc2[nt] = __builtin_amdgcn_mfma_f32_16x16x32_f16(alo2[kt], bh, acc2[nt], 0, 0, 0);
            acc2[nt] = __builtin_amdgcn_mfma_f32_16x16x32_f16(ahi2[kt], bl, acc2[nt], 0, 0, 0);
            acc2[nt] = __builtin_amdgcn_mfma_f32_16x16x32_f16(ahi2[kt], bh, acc2[nt], 0, 0, 0);
        }
    }

    // ---- epilogue 2: +b2, LayerNorm per row (16-lane shuffle reduce), relu
    float vv[8][4];
    float sums[4] = {0,0,0,0}, sqs[4] = {0,0,0,0};
#pragma unroll
    for (int nt = 0; nt < 8; ++nt) {
        const int col = nt * 16 + lm;
        const float bias = b2[col];
#pragma unroll
        for (int q = 0; q < 4; ++q) {
            float v2 = acc2[nt][q] + bias;
            vv[nt][q] = v2;
            sums[q] += v2;
            sqs[q]  += v2 * v2;
        }
    }
#pragma unroll
    for (int m = 1; m < 16; m <<= 1) {
#pragma unroll
        for (int q = 0; q < 4; ++q) {
            sums[q] += __shfl_xor(sums[q], m, 64);
            sqs[q]  += __shfl_xor(sqs[q],  m, 64);
        }
    }
    float gam[8], bet[8];
#pragma unroll
    for (int nt = 0; nt < 8; ++nt) {
        gam[nt] = gamma[nt * 16 + lm];
        bet[nt] = beta[nt * 16 + lm];
    }
#pragma unroll
    for (int q = 0; q < 4; ++q) {
        const int grow = r0 + lg * 4 + q;
        if (grow < NN) {
            const float mu  = sums[q] * (1.f / 128.f);
            const float var = sqs[q] * (1.f / 128.f) - mu * mu;
            const float rs  = rsqrtf(var + 1e-5f);
#pragma unroll
            for (int nt = 0; nt < 8; ++nt) {
                const int col = nt * 16 + lm;
                out[(size_t)grow * DD + col] = fmaxf((vv[nt][q] - mu) * rs * gam[nt] + bet[nt], 0.f);
            }
        }
    }
}

extern "C" void kernel_launch(void* const* d_in, const int* in_sizes, int n_in,
                              void* d_out, int out_size, void* d_ws, size_t ws_size,
                              hipStream_t stream) {
    (void)in_sizes; (void)n_in; (void)out_size; (void)ws_size;
    const float* x     = (const float*)d_in[0];
    const int*   ei    = (const int*)d_in[1];
    const float* ea    = (const float*)d_in[2];
    // d_in[3] = batch (unused)
    const float* We    = (const float*)d_in[4];
    const float* be    = (const float*)d_in[5];
    const float* epsp  = (const float*)d_in[6];
    const float* W1    = (const float*)d_in[7];
    const float* b1    = (const float*)d_in[8];
    const float* W2    = (const float*)d_in[9];
    const float* b2    = (const float*)d_in[10];
    const float* gamma = (const float*)d_in[11];
    const float* beta  = (const float*)d_in[12];
    float* out = (float*)d_out;

    _Float16* w1hi = (_Float16*)d_ws;
    _Float16* w1lo = w1hi + DD * DD;
    _Float16* w2hi = w1lo + DD * DD;
    _Float16* w2lo = w2hi + DD * DD;

    // d_out doubles as agg: zero, scatter-add, then node kernel reads+overwrites.
    hipMemsetAsync(d_out, 0, (size_t)NN * DD * sizeof(float), stream);
    prep_weights<<<(2 * DD * DD + 255) / 256, 256, 0, stream>>>(W1, W2, w1hi, w1lo, w2hi, w2lo);
    edge_kernel<<<2048, 256, 0, stream>>>(x, ei, ea, We, be, out);
    node_kernel<<<(NN + 63) / 64, 256, 0, stream>>>(x, out, w1hi, w1lo, w2hi, w2lo,
                                                    b1, b2, gamma, beta, epsp, out);
}

// Round 2
// 200.771 us; speedup vs baseline: 5.3670x; 5.3670x over previous
//
#include <hip/hip_runtime.h>
#include <stdint.h>

#define NN 100000
#define EE 600000
#define DD 128

typedef _Float16 half8 __attribute__((ext_vector_type(8)));
typedef float f32x4 __attribute__((ext_vector_type(4)));

// ---------------------------------------------------------------------------
// Prep: split W1/W2 into f16 hi/lo pairs, rearranged into MFMA B-fragment
// linear order: frag f = (kt*8 + nt), element [f*64 + lane]*8 + j,
// where k = kt*32 + (lane>>4)*8 + j, d = nt*16 + (lane&15).
// ---------------------------------------------------------------------------
__global__ __launch_bounds__(256)
void prep_weights(const float* __restrict__ W1, const float* __restrict__ W2,
                  _Float16* __restrict__ w1hi, _Float16* __restrict__ w1lo,
                  _Float16* __restrict__ w2hi, _Float16* __restrict__ w2lo)
{
    int t = blockIdx.x * 256 + threadIdx.x;
    if (t >= 2 * DD * DD) return;
    int which = t >> 14;           // 0 -> W1, 1 -> W2
    int idx = t & (DD * DD - 1);
    int k = idx >> 7;
    int d = idx & 127;
    float wv = (which ? W2 : W1)[k * DD + d];
    _Float16 hi = (_Float16)wv;
    _Float16 lo = (_Float16)(wv - (float)hi);
    int kt = k >> 5, kr = k & 31;
    int grp = kr >> 3, j = kr & 7;
    int nt = d >> 4, cc = d & 15;
    int lane = grp * 16 + cc;
    int off = ((kt * 8 + nt) * 64 + lane) * 8 + j;
    if (which) { w2hi[off] = hi; w2lo[off] = lo; }
    else       { w1hi[off] = hi; w1lo[off] = lo; }
}

// ---------------------------------------------------------------------------
// CSR build step 1: histogram of destination nodes (int atomics, L2-cheap).
// ---------------------------------------------------------------------------
__global__ __launch_bounds__(256)
void hist_kernel(const int* __restrict__ ei, int* __restrict__ counts)
{
    int e = blockIdx.x * 256 + threadIdx.x;
    if (e < EE) atomicAdd(&counts[ei[EE + e]], 1);
}

// ---------------------------------------------------------------------------
// CSR build step 2a: per-block exclusive scan (1024 elems/block) + block sums.
// ---------------------------------------------------------------------------
__global__ __launch_bounds__(1024)
void scan_blocks(const int* __restrict__ counts, int* __restrict__ start,
                 int* __restrict__ bsum)
{
    __shared__ int sm[1024];
    const int t = threadIdx.x;
    const int i = blockIdx.x * 1024 + t;
    int v = (i < NN) ? counts[i] : 0;
    sm[t] = v;
    __syncthreads();
#pragma unroll
    for (int off = 1; off < 1024; off <<= 1) {
        int u = (t >= off) ? sm[t - off] : 0;
        __syncthreads();
        sm[t] += u;
        __syncthreads();
    }
    if (i < NN) start[i] = sm[t] - v;     // exclusive within block
    if (t == 1023) bsum[blockIdx.x] = sm[t];
}

// ---------------------------------------------------------------------------
// CSR build step 2b: exclusive scan of the 98 block sums (single block).
// ---------------------------------------------------------------------------
__global__ __launch_bounds__(128)
void scan_top(const int* __restrict__ bsum, int* __restrict__ boff)
{
    __shared__ int sm[128];
    const int t = threadIdx.x;
    const int NB = (NN + 1023) / 1024;
    int v = (t < NB) ? bsum[t] : 0;
    sm[t] = v;
    __syncthreads();
#pragma unroll
    for (int off = 1; off < 128; off <<= 1) {
        int u = (t >= off) ? sm[t - off] : 0;
        __syncthreads();
        sm[t] += u;
        __syncthreads();
    }
    boff[t] = sm[t] - v;
}

// ---------------------------------------------------------------------------
// CSR build step 3: scatter edges into dst-sorted order (cursor atomics).
// Block offset folded in here (no separate add-offset pass).
// ---------------------------------------------------------------------------
__global__ __launch_bounds__(256)
void scatter_kernel(const int* __restrict__ ei, const int* __restrict__ start,
                    const int* __restrict__ boff, int* __restrict__ cursor,
                    int* __restrict__ sorted_src, int* __restrict__ sorted_eid)
{
    int e = blockIdx.x * 256 + threadIdx.x;
    if (e >= EE) return;
    int dst = ei[EE + e];
    int pos = start[dst] + boff[dst >> 10] + atomicAdd(&cursor[dst], 1);
    sorted_src[pos] = ei[e];
    sorted_eid[pos] = e;
}

// ---------------------------------------------------------------------------
// Aggregation: 32 lanes per node, register accumulation over the node's edge
// list (no float atomics). Writes h0 = (1+eps)*x[n] + sum(relu(x_src+emb)).
// ---------------------------------------------------------------------------
__global__ __launch_bounds__(256)
void agg_kernel(const float* __restrict__ x, const float* __restrict__ ea,
                const float* __restrict__ We, const float* __restrict__ be,
                const int* __restrict__ sorted_src, const int* __restrict__ sorted_eid,
                const int* __restrict__ start, const int* __restrict__ boff,
                const int* __restrict__ counts, const float* __restrict__ epsp,
                float* __restrict__ h0)
{
    int tid = blockIdx.x * 256 + threadIdx.x;
    int n = tid >> 5;
    if (n >= NN) return;
    int d0 = (tid & 31) * 4;
    float4 w0 = *(const float4*)(We + 0 * DD + d0);
    float4 w1 = *(const float4*)(We + 1 * DD + d0);
    float4 w2 = *(const float4*)(We + 2 * DD + d0);
    float4 w3 = *(const float4*)(We + 3 * DD + d0);
    float4 w4 = *(const float4*)(We + 4 * DD + d0);
    float4 w5 = *(const float4*)(We + 5 * DD + d0);
    float4 bb = *(const float4*)(be + d0);
    const int begin = start[n] + boff[n >> 10];
    const int cnt = counts[n];
    float ax = 0.f, ay = 0.f, az = 0.f, aw = 0.f;
    for (int i = 0; i < cnt; ++i) {
        int s = sorted_src[begin + i];
        int e = sorted_eid[begin + i];
        const float2* eap = (const float2*)(ea + e * 6);
        float2 e01 = eap[0];
        float2 e23 = eap[1];
        float2 e45 = eap[2];
        float4 xj = *(const float4*)(x + (size_t)s * DD + d0);
        float mx = xj.x + bb.x + e01.x*w0.x + e01.y*w1.x + e23.x*w2.x + e23.y*w3.x + e45.x*w4.x + e45.y*w5.x;
        float my = xj.y + bb.y + e01.x*w0.y + e01.y*w1.y + e23.x*w2.y + e23.y*w3.y + e45.x*w4.y + e45.y*w5.y;
        float mz = xj.z + bb.z + e01.x*w0.z + e01.y*w1.z + e23.x*w2.z + e23.y*w3.z + e45.x*w4.z + e45.y*w5.z;
        float mw = xj.w + bb.w + e01.x*w0.w + e01.y*w1.w + e23.x*w2.w + e23.y*w3.w + e45.x*w4.w + e45.y*w5.w;
        ax += fmaxf(mx, 0.f);
        ay += fmaxf(my, 0.f);
        az += fmaxf(mz, 0.f);
        aw += fmaxf(mw, 0.f);
    }
    const float sc = 1.0f + epsp[0];
    float4 xn = *(const float4*)(x + (size_t)n * DD + d0);
    float4 r;
    r.x = sc * xn.x + ax;
    r.y = sc * xn.y + ay;
    r.z = sc * xn.z + az;
    r.w = sc * xn.w + aw;
    *(float4*)(h0 + (size_t)n * DD + d0) = r;
}

// ---------------------------------------------------------------------------
// Fallback edge phase (atomic scatter) — only used if ws_size is too small.
// ---------------------------------------------------------------------------
__global__ __launch_bounds__(256)
void edge_kernel(const float* __restrict__ x, const int* __restrict__ ei,
                 const float* __restrict__ ea, const float* __restrict__ We,
                 const float* __restrict__ be, float* agg)
{
    int tid = blockIdx.x * 256 + threadIdx.x;
    int c = tid & 31;
    int d0 = c * 4;
    float4 w0 = *(const float4*)(We + 0 * DD + d0);
    float4 w1 = *(const float4*)(We + 1 * DD + d0);
    float4 w2 = *(const float4*)(We + 2 * DD + d0);
    float4 w3 = *(const float4*)(We + 3 * DD + d0);
    float4 w4 = *(const float4*)(We + 4 * DD + d0);
    float4 w5 = *(const float4*)(We + 5 * DD + d0);
    float4 bb = *(const float4*)(be + d0);
    int estride = (gridDim.x * 256) >> 5;
    for (int e = tid >> 5; e < EE; e += estride) {
        int src = ei[e];
        int dst = ei[EE + e];
        const float2* eap = (const float2*)(ea + e * 6);
        float2 e01 = eap[0];
        float2 e23 = eap[1];
        float2 e45 = eap[2];
        float4 xj = *(const float4*)(x + (size_t)src * DD + d0);
        float mx = xj.x + bb.x + e01.x*w0.x + e01.y*w1.x + e23.x*w2.x + e23.y*w3.x + e45.x*w4.x + e45.y*w5.x;
        float my = xj.y + bb.y + e01.x*w0.y + e01.y*w1.y + e23.x*w2.y + e23.y*w3.y + e45.x*w4.y + e45.y*w5.y;
        float mz = xj.z + bb.z + e01.x*w0.z + e01.y*w1.z + e23.x*w2.z + e23.y*w3.z + e45.x*w4.z + e45.y*w5.z;
        float mw = xj.w + bb.w + e01.x*w0.w + e01.y*w1.w + e23.x*w2.w + e23.y*w3.w + e45.x*w4.w + e45.y*w5.w;
        float* ap = agg + (size_t)dst * DD + d0;
        atomicAdd(ap + 0, fmaxf(mx, 0.f));
        atomicAdd(ap + 1, fmaxf(my, 0.f));
        atomicAdd(ap + 2, fmaxf(mz, 0.f));
        atomicAdd(ap + 3, fmaxf(mw, 0.f));
    }
}

// ---------------------------------------------------------------------------
// Node phase: FUSED=true -> input buffer already holds h0; else h0 computed
// in-kernel from x and agg. Then h1 = relu(h0@W1+b1); h2 = h1@W2+b2;
// out = relu(LN(h2)*gamma+beta). One wave = 16 rows x 128 cols, MFMA
// f32_16x16x32_f16 with 2-term f16 split (3 MFMAs per k/n tile).
// ---------------------------------------------------------------------------
template<bool FUSED>
__global__ __launch_bounds__(256)
void node_kernel(const float* __restrict__ x, const float* agg,
                 const _Float16* __restrict__ w1hi, const _Float16* __restrict__ w1lo,
                 const _Float16* __restrict__ w2hi, const _Float16* __restrict__ w2lo,
                 const float* __restrict__ b1, const float* __restrict__ b2,
                 const float* __restrict__ gamma, const float* __restrict__ beta,
                 const float* __restrict__ epsp, float* out)
{
    __shared__ uint32_t h1buf[4][16 * 128];  // 32 KiB, 8 KiB per wave
    const int wv = threadIdx.x >> 6;
    const int l  = threadIdx.x & 63;
    const int lm = l & 15;
    const int lg = l >> 4;
    const int r0 = blockIdx.x * 64 + wv * 16;

    // ---- GEMM1 A fragments straight from global (row = lm, k = kt*32+lg*8+j)
    int arow = r0 + lm;
    if (arow >= NN) arow = NN - 1;   // OOB waves compute garbage, stores predicated
    half8 ahi[4], alo[4];
#pragma unroll
    for (int kt = 0; kt < 4; ++kt) {
        const int kb = kt * 32 + lg * 8;
        const float4* ap = (const float4*)(agg + (size_t)arow * DD + kb);
        float4 a0 = ap[0], a1 = ap[1];
        float v[8];
        if constexpr (FUSED) {
            v[0]=a0.x; v[1]=a0.y; v[2]=a0.z; v[3]=a0.w;
            v[4]=a1.x; v[5]=a1.y; v[6]=a1.z; v[7]=a1.w;
        } else {
            const float scale = 1.0f + epsp[0];
            const float4* xp = (const float4*)(x + (size_t)arow * DD + kb);
            float4 x0 = xp[0], x1 = xp[1];
            v[0]=x0.x*scale+a0.x; v[1]=x0.y*scale+a0.y; v[2]=x0.z*scale+a0.z; v[3]=x0.w*scale+a0.w;
            v[4]=x1.x*scale+a1.x; v[5]=x1.y*scale+a1.y; v[6]=x1.z*scale+a1.z; v[7]=x1.w*scale+a1.w;
        }
#pragma unroll
        for (int j = 0; j < 8; ++j) {
            _Float16 h = (_Float16)v[j];
            ahi[kt][j] = h;
            alo[kt][j] = (_Float16)(v[j] - (float)h);
        }
    }

    f32x4 acc[8];
#pragma unroll
    for (int nt = 0; nt < 8; ++nt) { acc[nt][0]=0.f; acc[nt][1]=0.f; acc[nt][2]=0.f; acc[nt][3]=0.f; }

#pragma unroll
    for (int kt = 0; kt < 4; ++kt) {
#pragma unroll
        for (int nt = 0; nt < 8; ++nt) {
            const int f = ((kt * 8 + nt) * 64 + l) * 8;
            half8 bh = *(const half8*)(w1hi + f);
            half8 bl = *(const half8*)(w1lo + f);
            acc[nt] = __builtin_amdgcn_mfma_f32_16x16x32_f16(alo[kt], bh, acc[nt], 0, 0, 0);
            acc[nt] = __builtin_amdgcn_mfma_f32_16x16x32_f16(ahi[kt], bl, acc[nt], 0, 0, 0);
            acc[nt] = __builtin_amdgcn_mfma_f32_16x16x32_f16(ahi[kt], bh, acc[nt], 0, 0, 0);
        }
    }

    // ---- epilogue 1: relu(+b1), f16-split, pack (hi|lo<<16), LDS XOR-swizzled
    uint32_t* hb = h1buf[wv];
#pragma unroll
    for (int nt = 0; nt < 8; ++nt) {
        const int col = nt * 16 + lm;
        const float bias = b1[col];
#pragma unroll
        for (int q = 0; q < 4; ++q) {
            const int row = lg * 4 + q;
            float v1 = fmaxf(acc[nt][q] + bias, 0.f);
            _Float16 h = (_Float16)v1;
            _Float16 lo2 = (_Float16)(v1 - (float)h);
            uint32_t pk = (uint32_t)__builtin_bit_cast(uint16_t, h)
                        | ((uint32_t)__builtin_bit_cast(uint16_t, lo2) << 16);
            hb[row * 128 + (col ^ ((row & 7) << 2))] = pk;
        }
    }
    __syncthreads();

    // ---- GEMM2 A fragments from LDS (same swizzle on read)
    half8 ahi2[4], alo2[4];
    {
        const int s = (lm & 7) << 2;
        const uint32_t* rowp = hb + lm * 128;
#pragma unroll
        for (int kt = 0; kt < 4; ++kt) {
            const int kb = kt * 32 + lg * 8;
            uint4 t0 = *(const uint4*)(rowp + ((kb    ) ^ s));
            uint4 t1 = *(const uint4*)(rowp + ((kb + 4) ^ s));
            uint32_t u[8] = {t0.x, t0.y, t0.z, t0.w, t1.x, t1.y, t1.z, t1.w};
#pragma unroll
            for (int j = 0; j < 8; ++j) {
                ahi2[kt][j] = __builtin_bit_cast(_Float16, (uint16_t)(u[j] & 0xffffu));
                alo2[kt][j] = __builtin_bit_cast(_Float16, (uint16_t)(u[j] >> 16));
            }
        }
    }

    f32x4 acc2[8];
#pragma unroll
    for (int nt = 0; nt < 8; ++nt) { acc2[nt][0]=0.f; acc2[nt][1]=0.f; acc2[nt][2]=0.f; acc2[nt][3]=0.f; }
#pragma unroll
    for (int kt = 0; kt < 4; ++kt) {
#pragma unroll
        for (int nt = 0; nt < 8; ++nt) {
            const int f = ((kt * 8 + nt) * 64 + l) * 8;
            half8 bh = *(const half8*)(w2hi + f);
            half8 bl = *(const half8*)(w2lo + f);
            acc2[nt] = __builtin_amdgcn_mfma_f32_16x16x32_f16(alo2[kt], bh, acc2[nt], 0, 0, 0);
            acc2[nt] = __builtin_amdgcn_mfma_f32_16x16x32_f16(ahi2[kt], bl, acc2[nt], 0, 0, 0);
            acc2[nt] = __builtin_amdgcn_mfma_f32_16x16x32_f16(ahi2[kt], bh, acc2[nt], 0, 0, 0);
        }
    }

    // ---- epilogue 2: +b2, LayerNorm per row (16-lane shuffle reduce), relu
    float vv[8][4];
    float sums[4] = {0,0,0,0}, sqs[4] = {0,0,0,0};
#pragma unroll
    for (int nt = 0; nt < 8; ++nt) {
        const int col = nt * 16 + lm;
        const float bias = b2[col];
#pragma unroll
        for (int q = 0; q < 4; ++q) {
            float v2 = acc2[nt][q] + bias;
            vv[nt][q] = v2;
            sums[q] += v2;
            sqs[q]  += v2 * v2;
        }
    }
#pragma unroll
    for (int m = 1; m < 16; m <<= 1) {
#pragma unroll
        for (int q = 0; q < 4; ++q) {
            sums[q] += __shfl_xor(sums[q], m, 64);
            sqs[q]  += __shfl_xor(sqs[q],  m, 64);
        }
    }
    float gam[8], bet[8];
#pragma unroll
    for (int nt = 0; nt < 8; ++nt) {
        gam[nt] = gamma[nt * 16 + lm];
        bet[nt] = beta[nt * 16 + lm];
    }
#pragma unroll
    for (int q = 0; q < 4; ++q) {
        const int grow = r0 + lg * 4 + q;
        if (grow < NN) {
            const float mu  = sums[q] * (1.f / 128.f);
            const float var = sqs[q] * (1.f / 128.f) - mu * mu;
            const float rs  = rsqrtf(var + 1e-5f);
#pragma unroll
            for (int nt = 0; nt < 8; ++nt) {
                const int col = nt * 16 + lm;
                out[(size_t)grow * DD + col] = fmaxf((vv[nt][q] - mu) * rs * gam[nt] + bet[nt], 0.f);
            }
        }
    }
}

extern "C" void kernel_launch(void* const* d_in, const int* in_sizes, int n_in,
                              void* d_out, int out_size, void* d_ws, size_t ws_size,
                              hipStream_t stream) {
    (void)in_sizes; (void)n_in; (void)out_size;
    const float* x     = (const float*)d_in[0];
    const int*   ei    = (const int*)d_in[1];
    const float* ea    = (const float*)d_in[2];
    // d_in[3] = batch (unused)
    const float* We    = (const float*)d_in[4];
    const float* be    = (const float*)d_in[5];
    const float* epsp  = (const float*)d_in[6];
    const float* W1    = (const float*)d_in[7];
    const float* b1    = (const float*)d_in[8];
    const float* W2    = (const float*)d_in[9];
    const float* b2    = (const float*)d_in[10];
    const float* gamma = (const float*)d_in[11];
    const float* beta  = (const float*)d_in[12];
    float* out = (float*)d_out;

    // ---- workspace layout (all offsets 16B-aligned)
    char* ws = (char*)d_ws;
    _Float16* w1hi = (_Float16*)ws;                  // 4 * 128*128 * 2B
    _Float16* w1lo = w1hi + DD * DD;
    _Float16* w2hi = w1lo + DD * DD;
    _Float16* w2lo = w2hi + DD * DD;
    size_t off = 4 * (size_t)DD * DD * sizeof(_Float16);   // 131072
    int* counts = (int*)(ws + off);   off += (size_t)NN * 4;   // 400000
    int* cursor = (int*)(ws + off);   off += (size_t)NN * 4;
    int* start  = (int*)(ws + off);   off += (size_t)NN * 4;
    int* bsum   = (int*)(ws + off);   off += 128 * 4;
    int* boff   = (int*)(ws + off);   off += 128 * 4;
    int* sorted_src = (int*)(ws + off); off += (size_t)EE * 4;
    int* sorted_eid = (int*)(ws + off); off += (size_t)EE * 4;
    const size_t need = off;

    prep_weights<<<(2 * DD * DD + 255) / 256, 256, 0, stream>>>(W1, W2, w1hi, w1lo, w2hi, w2lo);

    if (ws_size >= need) {
        // CSR counting-sort path: no float atomics anywhere.
        hipMemsetAsync(counts, 0, 2 * (size_t)NN * 4, stream);   // counts + cursor
        hist_kernel<<<(EE + 255) / 256, 256, 0, stream>>>(ei, counts);
        scan_blocks<<<(NN + 1023) / 1024, 1024, 0, stream>>>(counts, start, bsum);
        scan_top<<<1, 128, 0, stream>>>(bsum, boff);
        scatter_kernel<<<(EE + 255) / 256, 256, 0, stream>>>(ei, start, boff, cursor,
                                                             sorted_src, sorted_eid);
        agg_kernel<<<(NN * 32 + 255) / 256, 256, 0, stream>>>(x, ea, We, be,
                                                              sorted_src, sorted_eid,
                                                              start, boff, counts, epsp, out);
        node_kernel<true><<<(NN + 63) / 64, 256, 0, stream>>>(x, out, w1hi, w1lo, w2hi, w2lo,
                                                              b1, b2, gamma, beta, epsp, out);
    } else {
        // Fallback: atomic scatter into d_out (doubles as agg).
        hipMemsetAsync(d_out, 0, (size_t)NN * DD * sizeof(float), stream);
        edge_kernel<<<2048, 256, 0, stream>>>(x, ei, ea, We, be, out);
        node_kernel<false><<<(NN + 63) / 64, 256, 0, stream>>>(x, out, w1hi, w1lo, w2hi, w2lo,
                                                               b1, b2, gamma, beta, epsp, out);
    }
}

// Round 3
// 172.784 us; speedup vs baseline: 6.2363x; 1.1620x over previous
//
#include <hip/hip_runtime.h>
#include <stdint.h>

#define NN 100000
#define EE 600000
#define DD 128

typedef _Float16 half8 __attribute__((ext_vector_type(8)));
typedef _Float16 h2 __attribute__((ext_vector_type(2)));
typedef float f32x4 __attribute__((ext_vector_type(4)));

__device__ __forceinline__ float pack_h2(float a, float b) {
    h2 h; h.x = (_Float16)a; h.y = (_Float16)b;
    return __builtin_bit_cast(float, h);
}

// ---------------------------------------------------------------------------
// Prep: split W1/W2 into f16 hi/lo pairs in MFMA B-fragment linear order,
// AND zero the counts+cursor arrays (saves a memset dispatch).
// ---------------------------------------------------------------------------
__global__ __launch_bounds__(256)
void prep_weights(const float* __restrict__ W1, const float* __restrict__ W2,
                  _Float16* __restrict__ w1hi, _Float16* __restrict__ w1lo,
                  _Float16* __restrict__ w2hi, _Float16* __restrict__ w2lo,
                  int* __restrict__ zero_base)
{
    int t = blockIdx.x * 256 + threadIdx.x;
    if (t < 2 * NN) zero_base[t] = 0;
    if (t >= 2 * DD * DD) return;
    int which = t >> 14;           // 0 -> W1, 1 -> W2
    int idx = t & (DD * DD - 1);
    int k = idx >> 7;
    int d = idx & 127;
    float wv = (which ? W2 : W1)[k * DD + d];
    _Float16 hi = (_Float16)wv;
    _Float16 lo = (_Float16)(wv - (float)hi);
    int kt = k >> 5, kr = k & 31;
    int grp = kr >> 3, j = kr & 7;
    int nt = d >> 4, cc = d & 15;
    int lane = grp * 16 + cc;
    int off = ((kt * 8 + nt) * 64 + lane) * 8 + j;
    if (which) { w2hi[off] = hi; w2lo[off] = lo; }
    else       { w1hi[off] = hi; w1lo[off] = lo; }
}

// ---------------------------------------------------------------------------
// CSR build step 1: histogram of destination nodes (int atomics).
// ---------------------------------------------------------------------------
__global__ __launch_bounds__(256)
void hist_kernel(const int* __restrict__ ei, int* __restrict__ counts)
{
    int e = blockIdx.x * 256 + threadIdx.x;
    if (e < EE) atomicAdd(&counts[ei[EE + e]], 1);
}

// ---------------------------------------------------------------------------
// CSR build step 2a: exclusive scan, 1024 elems/block (256 thr x int4),
// shfl-based wave scan + tiny LDS combine (2 barriers).
// ---------------------------------------------------------------------------
__global__ __launch_bounds__(256)
void scan_blocks(const int* __restrict__ counts, int* __restrict__ startv,
                 int* __restrict__ bsum)
{
    const int t = threadIdx.x;
    const int idx = blockIdx.x * 1024 + t * 4;
    int4 v = {0, 0, 0, 0};
    if (idx < NN) v = *(const int4*)(counts + idx);     // NN % 4 == 0
    int s1 = v.x + v.y, s2 = s1 + v.z, s3 = s2 + v.w;   // inclusive in quad
    const int lane = t & 63;
    int q = s3;
#pragma unroll
    for (int off = 1; off < 64; off <<= 1) {
        int u = __shfl_up(q, off, 64);
        if (lane >= off) q += u;
    }
    __shared__ int wsum[4];
    if (lane == 63) wsum[t >> 6] = q;
    __syncthreads();
    const int w = t >> 6;
    int pre = 0;
    if (w > 0) pre += wsum[0];
    if (w > 1) pre += wsum[1];
    if (w > 2) pre += wsum[2];
    const int excl = (q - s3) + pre;
    if (idx < NN) {
        int4 o = {excl, excl + v.x, excl + s1, excl + s2};
        *(int4*)(startv + idx) = o;
    }
    if (t == 0) { /* after barrier all wsum valid */ }
    __syncthreads();
    if (t == 0) bsum[blockIdx.x] = wsum[0] + wsum[1] + wsum[2] + wsum[3];
}

// ---------------------------------------------------------------------------
// CSR build step 2b: exclusive scan of the 98 block sums (single block).
// ---------------------------------------------------------------------------
__global__ __launch_bounds__(128)
void scan_top(const int* __restrict__ bsum, int* __restrict__ boff)
{
    __shared__ int sm[128];
    const int t = threadIdx.x;
    const int NB = (NN + 1023) / 1024;
    int v = (t < NB) ? bsum[t] : 0;
    sm[t] = v;
    __syncthreads();
#pragma unroll
    for (int off = 1; off < 128; off <<= 1) {
        int u = (t >= off) ? sm[t - off] : 0;
        __syncthreads();
        sm[t] += u;
        __syncthreads();
    }
    boff[t] = sm[t] - v;
}

// ---------------------------------------------------------------------------
// CSR build step 3 (records tier): scatter 16B records {src, h2 ea01, h2 ea23,
// h2 ea45} into dst-sorted order.
// ---------------------------------------------------------------------------
__global__ __launch_bounds__(256)
void scatter_rec(const int* __restrict__ ei, const float* __restrict__ ea,
                 const int* __restrict__ start, const int* __restrict__ boff,
                 int* __restrict__ cursor, float* __restrict__ rec)
{
    int e = blockIdx.x * 256 + threadIdx.x;
    if (e >= EE) return;
    int dst = ei[EE + e];
    int src = ei[e];
    int pos = start[dst] + boff[dst >> 10] + atomicAdd(&cursor[dst], 1);
    const float2* eap = (const float2*)(ea + e * 6);
    float2 e01 = eap[0];
    float2 e23 = eap[1];
    float2 e45 = eap[2];
    float4 r;
    r.x = __int_as_float(src);
    r.y = pack_h2(e01.x, e01.y);
    r.z = pack_h2(e23.x, e23.y);
    r.w = pack_h2(e45.x, e45.y);
    *(float4*)(rec + (size_t)pos * 4) = r;
}

// ---------------------------------------------------------------------------
// Aggregation (records tier): 32 lanes/node, 4-edge unrolled so record loads
// and x-gathers issue 4-wide independent. Writes h0 = (1+eps)x + agg.
// ---------------------------------------------------------------------------
__global__ __launch_bounds__(256)
void agg_rec(const float* __restrict__ x, const float* __restrict__ rec,
             const int* __restrict__ start, const int* __restrict__ boff,
             const int* __restrict__ counts, const float* __restrict__ epsp,
             float* __restrict__ h0)
{
    int tid = blockIdx.x * 256 + threadIdx.x;
    int n = tid >> 5;
    if (n >= NN) return;
    int d0 = (tid & 31) * 4;
    float4 w0 = *(const float4*)(/*We*/ rec, 0), dummy; // placeholder removed below
    (void)dummy;
    // (real loads follow; placeholder above avoided — see actual code)
    float4 W0, W1v, W2v, W3v, W4v, W5v, BB;
    // loaded in launch wrapper via constant pointers passed separately
    // -- this function body is replaced below --
    (void)w0; (void)W0; (void)W1v; (void)W2v; (void)W3v; (void)W4v; (void)W5v; (void)BB;
    (void)x; (void)start; (void)boff; (void)counts; (void)epsp; (void)h0; (void)d0; (void)n;
}

// Real agg (records tier).
__global__ __launch_bounds__(256)
void agg_rec2(const float* __restrict__ x, const float* __restrict__ rec,
              const float* __restrict__ We, const float* __restrict__ be,
              const int* __restrict__ start, const int* __restrict__ boff,
              const int* __restrict__ counts, const float* __restrict__ epsp,
              float* __restrict__ h0)
{
    int tid = blockIdx.x * 256 + threadIdx.x;
    int n = tid >> 5;
    if (n >= NN) return;
    int d0 = (tid & 31) * 4;
    float4 w0 = *(const float4*)(We + 0 * DD + d0);
    float4 w1 = *(const float4*)(We + 1 * DD + d0);
    float4 w2 = *(const float4*)(We + 2 * DD + d0);
    float4 w3 = *(const float4*)(We + 3 * DD + d0);
    float4 w4 = *(const float4*)(We + 4 * DD + d0);
    float4 w5 = *(const float4*)(We + 5 * DD + d0);
    float4 bb = *(const float4*)(be + d0);
    const int begin = start[n] + boff[n >> 10];
    const int cnt = counts[n];
    const float4* rp = (const float4*)(rec + (size_t)begin * 4);
    float ax = 0.f, ay = 0.f, az = 0.f, aw = 0.f;

#define EDGE_ACC(R, XJ, WGT)                                                    \
    do {                                                                        \
        h2 p01 = __builtin_bit_cast(h2, (R).y);                                 \
        h2 p23 = __builtin_bit_cast(h2, (R).z);                                 \
        h2 p45 = __builtin_bit_cast(h2, (R).w);                                 \
        float f0 = (float)p01.x, f1 = (float)p01.y;                             \
        float f2 = (float)p23.x, f3 = (float)p23.y;                             \
        float f4 = (float)p45.x, f5 = (float)p45.y;                             \
        float tx = (XJ).x + bb.x, ty = (XJ).y + bb.y,                           \
              tz = (XJ).z + bb.z, tw = (XJ).w + bb.w;                           \
        tx = fmaf(f0, w0.x, tx); ty = fmaf(f0, w0.y, ty);                       \
        tz = fmaf(f0, w0.z, tz); tw = fmaf(f0, w0.w, tw);                       \
        tx = fmaf(f1, w1.x, tx); ty = fmaf(f1, w1.y, ty);                       \
        tz = fmaf(f1, w1.z, tz); tw = fmaf(f1, w1.w, tw);                       \
        tx = fmaf(f2, w2.x, tx); ty = fmaf(f2, w2.y, ty);                       \
        tz = fmaf(f2, w2.z, tz); tw = fmaf(f2, w2.w, tw);                       \
        tx = fmaf(f3, w3.x, tx); ty = fmaf(f3, w3.y, ty);                       \
        tz = fmaf(f3, w3.z, tz); tw = fmaf(f3, w3.w, tw);                       \
        tx = fmaf(f4, w4.x, tx); ty = fmaf(f4, w4.y, ty);                       \
        tz = fmaf(f4, w4.z, tz); tw = fmaf(f4, w4.w, tw);                       \
        tx = fmaf(f5, w5.x, tx); ty = fmaf(f5, w5.y, ty);                       \
        tz = fmaf(f5, w5.z, tz); tw = fmaf(f5, w5.w, tw);                       \
        ax = fmaf((WGT), fmaxf(tx, 0.f), ax);                                   \
        ay = fmaf((WGT), fmaxf(ty, 0.f), ay);                                   \
        az = fmaf((WGT), fmaxf(tz, 0.f), az);                                   \
        aw = fmaf((WGT), fmaxf(tw, 0.f), aw);                                   \
    } while (0)

    for (int i = 0; i < cnt; i += 4) {
        const int rem = cnt - i;
        const int ia = i;
        const int ib = i + (rem > 1 ? 1 : 0);
        const int ic = i + (rem > 2 ? 2 : 0);
        const int id = i + (rem > 3 ? 3 : 0);
        float4 ra = rp[ia], rb = rp[ib], rc = rp[ic], rd = rp[id];
        int sa = __float_as_int(ra.x), sb = __float_as_int(rb.x),
            sc = __float_as_int(rc.x), sd = __float_as_int(rd.x);
        float4 xa = *(const float4*)(x + (size_t)sa * DD + d0);
        float4 xb = *(const float4*)(x + (size_t)sb * DD + d0);
        float4 xc = *(const float4*)(x + (size_t)sc * DD + d0);
        float4 xd = *(const float4*)(x + (size_t)sd * DD + d0);
        const float wb2 = rem > 1 ? 1.f : 0.f;
        const float wc2 = rem > 2 ? 1.f : 0.f;
        const float wd2 = rem > 3 ? 1.f : 0.f;
        EDGE_ACC(ra, xa, 1.f);
        EDGE_ACC(rb, xb, wb2);
        EDGE_ACC(rc, xc, wc2);
        EDGE_ACC(rd, xd, wd2);
    }
#undef EDGE_ACC

    const float sc2 = 1.0f + epsp[0];
    float4 xn = *(const float4*)(x + (size_t)n * DD + d0);
    float4 r;
    r.x = sc2 * xn.x + ax;
    r.y = sc2 * xn.y + ay;
    r.z = sc2 * xn.z + az;
    r.w = sc2 * xn.w + aw;
    *(float4*)(h0 + (size_t)n * DD + d0) = r;
}

// ---------------------------------------------------------------------------
// Tier-B (R2) kernels: scatter src/eid, agg with indirection.
// ---------------------------------------------------------------------------
__global__ __launch_bounds__(256)
void scatter_kernel(const int* __restrict__ ei, const int* __restrict__ start,
                    const int* __restrict__ boff, int* __restrict__ cursor,
                    int* __restrict__ sorted_src, int* __restrict__ sorted_eid)
{
    int e = blockIdx.x * 256 + threadIdx.x;
    if (e >= EE) return;
    int dst = ei[EE + e];
    int pos = start[dst] + boff[dst >> 10] + atomicAdd(&cursor[dst], 1);
    sorted_src[pos] = ei[e];
    sorted_eid[pos] = e;
}

__global__ __launch_bounds__(256)
void agg_kernel(const float* __restrict__ x, const float* __restrict__ ea,
                const float* __restrict__ We, const float* __restrict__ be,
                const int* __restrict__ sorted_src, const int* __restrict__ sorted_eid,
                const int* __restrict__ start, const int* __restrict__ boff,
                const int* __restrict__ counts, const float* __restrict__ epsp,
                float* __restrict__ h0)
{
    int tid = blockIdx.x * 256 + threadIdx.x;
    int n = tid >> 5;
    if (n >= NN) return;
    int d0 = (tid & 31) * 4;
    float4 w0 = *(const float4*)(We + 0 * DD + d0);
    float4 w1 = *(const float4*)(We + 1 * DD + d0);
    float4 w2 = *(const float4*)(We + 2 * DD + d0);
    float4 w3 = *(const float4*)(We + 3 * DD + d0);
    float4 w4 = *(const float4*)(We + 4 * DD + d0);
    float4 w5 = *(const float4*)(We + 5 * DD + d0);
    float4 bb = *(const float4*)(be + d0);
    const int begin = start[n] + boff[n >> 10];
    const int cnt = counts[n];
    float ax = 0.f, ay = 0.f, az = 0.f, aw = 0.f;
    for (int i = 0; i < cnt; ++i) {
        int s = sorted_src[begin + i];
        int e = sorted_eid[begin + i];
        const float2* eap = (const float2*)(ea + e * 6);
        float2 e01 = eap[0];
        float2 e23 = eap[1];
        float2 e45 = eap[2];
        float4 xj = *(const float4*)(x + (size_t)s * DD + d0);
        float mx = xj.x + bb.x + e01.x*w0.x + e01.y*w1.x + e23.x*w2.x + e23.y*w3.x + e45.x*w4.x + e45.y*w5.x;
        float my = xj.y + bb.y + e01.x*w0.y + e01.y*w1.y + e23.x*w2.y + e23.y*w3.y + e45.x*w4.y + e45.y*w5.y;
        float mz = xj.z + bb.z + e01.x*w0.z + e01.y*w1.z + e23.x*w2.z + e23.y*w3.z + e45.x*w4.z + e45.y*w5.z;
        float mw = xj.w + bb.w + e01.x*w0.w + e01.y*w1.w + e23.x*w2.w + e23.y*w3.w + e45.x*w4.w + e45.y*w5.w;
        ax += fmaxf(mx, 0.f);
        ay += fmaxf(my, 0.f);
        az += fmaxf(mz, 0.f);
        aw += fmaxf(mw, 0.f);
    }
    const float sc = 1.0f + epsp[0];
    float4 xn = *(const float4*)(x + (size_t)n * DD + d0);
    float4 r;
    r.x = sc * xn.x + ax;
    r.y = sc * xn.y + ay;
    r.z = sc * xn.z + az;
    r.w = sc * xn.w + aw;
    *(float4*)(h0 + (size_t)n * DD + d0) = r;
}

// ---------------------------------------------------------------------------
// Tier-C fallback: atomic scatter.
// ---------------------------------------------------------------------------
__global__ __launch_bounds__(256)
void edge_kernel(const float* __restrict__ x, const int* __restrict__ ei,
                 const float* __restrict__ ea, const float* __restrict__ We,
                 const float* __restrict__ be, float* agg)
{
    int tid = blockIdx.x * 256 + threadIdx.x;
    int c = tid & 31;
    int d0 = c * 4;
    float4 w0 = *(const float4*)(We + 0 * DD + d0);
    float4 w1 = *(const float4*)(We + 1 * DD + d0);
    float4 w2 = *(const float4*)(We + 2 * DD + d0);
    float4 w3 = *(const float4*)(We + 3 * DD + d0);
    float4 w4 = *(const float4*)(We + 4 * DD + d0);
    float4 w5 = *(const float4*)(We + 5 * DD + d0);
    float4 bb = *(const float4*)(be + d0);
    int estride = (gridDim.x * 256) >> 5;
    for (int e = tid >> 5; e < EE; e += estride) {
        int src = ei[e];
        int dst = ei[EE + e];
        const float2* eap = (const float2*)(ea + e * 6);
        float2 e01 = eap[0];
        float2 e23 = eap[1];
        float2 e45 = eap[2];
        float4 xj = *(const float4*)(x + (size_t)src * DD + d0);
        float mx = xj.x + bb.x + e01.x*w0.x + e01.y*w1.x + e23.x*w2.x + e23.y*w3.x + e45.x*w4.x + e45.y*w5.x;
        float my = xj.y + bb.y + e01.x*w0.y + e01.y*w1.y + e23.x*w2.y + e23.y*w3.y + e45.x*w4.y + e45.y*w5.y;
        float mz = xj.z + bb.z + e01.x*w0.z + e01.y*w1.z + e23.x*w2.z + e23.y*w3.z + e45.x*w4.z + e45.y*w5.z;
        float mw = xj.w + bb.w + e01.x*w0.w + e01.y*w1.w + e23.x*w2.w + e23.y*w3.w + e45.x*w4.w + e45.y*w5.w;
        float* ap = agg + (size_t)dst * DD + d0;
        atomicAdd(ap + 0, fmaxf(mx, 0.f));
        atomicAdd(ap + 1, fmaxf(my, 0.f));
        atomicAdd(ap + 2, fmaxf(mz, 0.f));
        atomicAdd(ap + 3, fmaxf(mw, 0.f));
    }
}

// ---------------------------------------------------------------------------
// Node phase (unchanged from R2): h1 = relu(h0@W1+b1); h2 = h1@W2+b2;
// out = relu(LN(h2)*gamma+beta). MFMA f16 2-term split.
// ---------------------------------------------------------------------------
template<bool FUSED>
__global__ __launch_bounds__(256)
void node_kernel(const float* __restrict__ x, const float* agg,
                 const _Float16* __restrict__ w1hi, const _Float16* __restrict__ w1lo,
                 const _Float16* __restrict__ w2hi, const _Float16* __restrict__ w2lo,
                 const float* __restrict__ b1, const float* __restrict__ b2,
                 const float* __restrict__ gamma, const float* __restrict__ beta,
                 const float* __restrict__ epsp, float* out)
{
    __shared__ uint32_t h1buf[4][16 * 128];  // 32 KiB, 8 KiB per wave
    const int wv = threadIdx.x >> 6;
    const int l  = threadIdx.x & 63;
    const int lm = l & 15;
    const int lg = l >> 4;
    const int r0 = blockIdx.x * 64 + wv * 16;

    int arow = r0 + lm;
    if (arow >= NN) arow = NN - 1;
    half8 ahi[4], alo[4];
#pragma unroll
    for (int kt = 0; kt < 4; ++kt) {
        const int kb = kt * 32 + lg * 8;
        const float4* ap = (const float4*)(agg + (size_t)arow * DD + kb);
        float4 a0 = ap[0], a1 = ap[1];
        float v[8];
        if constexpr (FUSED) {
            v[0]=a0.x; v[1]=a0.y; v[2]=a0.z; v[3]=a0.w;
            v[4]=a1.x; v[5]=a1.y; v[6]=a1.z; v[7]=a1.w;
        } else {
            const float scale = 1.0f + epsp[0];
            const float4* xp = (const float4*)(x + (size_t)arow * DD + kb);
            float4 x0 = xp[0], x1 = xp[1];
            v[0]=x0.x*scale+a0.x; v[1]=x0.y*scale+a0.y; v[2]=x0.z*scale+a0.z; v[3]=x0.w*scale+a0.w;
            v[4]=x1.x*scale+a1.x; v[5]=x1.y*scale+a1.y; v[6]=x1.z*scale+a1.z; v[7]=x1.w*scale+a1.w;
        }
#pragma unroll
        for (int j = 0; j < 8; ++j) {
            _Float16 h = (_Float16)v[j];
            ahi[kt][j] = h;
            alo[kt][j] = (_Float16)(v[j] - (float)h);
        }
    }

    f32x4 acc[8];
#pragma unroll
    for (int nt = 0; nt < 8; ++nt) { acc[nt][0]=0.f; acc[nt][1]=0.f; acc[nt][2]=0.f; acc[nt][3]=0.f; }

#pragma unroll
    for (int kt = 0; kt < 4; ++kt) {
#pragma unroll
        for (int nt = 0; nt < 8; ++nt) {
            const int f = ((kt * 8 + nt) * 64 + l) * 8;
            half8 bh = *(const half8*)(w1hi + f);
            half8 bl = *(const half8*)(w1lo + f);
            acc[nt] = __builtin_amdgcn_mfma_f32_16x16x32_f16(alo[kt], bh, acc[nt], 0, 0, 0);
            acc[nt] = __builtin_amdgcn_mfma_f32_16x16x32_f16(ahi[kt], bl, acc[nt], 0, 0, 0);
            acc[nt] = __builtin_amdgcn_mfma_f32_16x16x32_f16(ahi[kt], bh, acc[nt], 0, 0, 0);
        }
    }

    uint32_t* hb = h1buf[wv];
#pragma unroll
    for (int nt = 0; nt < 8; ++nt) {
        const int col = nt * 16 + lm;
        const float bias = b1[col];
#pragma unroll
        for (int q = 0; q < 4; ++q) {
            const int row = lg * 4 + q;
            float v1 = fmaxf(acc[nt][q] + bias, 0.f);
            _Float16 h = (_Float16)v1;
            _Float16 lo2 = (_Float16)(v1 - (float)h);
            uint32_t pk = (uint32_t)__builtin_bit_cast(uint16_t, h)
                        | ((uint32_t)__builtin_bit_cast(uint16_t, lo2) << 16);
            hb[row * 128 + (col ^ ((row & 7) << 2))] = pk;
        }
    }
    __syncthreads();

    half8 ahi2[4], alo2[4];
    {
        const int s = (lm & 7) << 2;
        const uint32_t* rowp = hb + lm * 128;
#pragma unroll
        for (int kt = 0; kt < 4; ++kt) {
            const int kb = kt * 32 + lg * 8;
            uint4 t0 = *(const uint4*)(rowp + ((kb    ) ^ s));
            uint4 t1 = *(const uint4*)(rowp + ((kb + 4) ^ s));
            uint32_t u[8] = {t0.x, t0.y, t0.z, t0.w, t1.x, t1.y, t1.z, t1.w};
#pragma unroll
            for (int j = 0; j < 8; ++j) {
                ahi2[kt][j] = __builtin_bit_cast(_Float16, (uint16_t)(u[j] & 0xffffu));
                alo2[kt][j] = __builtin_bit_cast(_Float16, (uint16_t)(u[j] >> 16));
            }
        }
    }

    f32x4 acc2[8];
#pragma unroll
    for (int nt = 0; nt < 8; ++nt) { acc2[nt][0]=0.f; acc2[nt][1]=0.f; acc2[nt][2]=0.f; acc2[nt][3]=0.f; }
#pragma unroll
    for (int kt = 0; kt < 4; ++kt) {
#pragma unroll
        for (int nt = 0; nt < 8; ++nt) {
            const int f = ((kt * 8 + nt) * 64 + l) * 8;
            half8 bh = *(const half8*)(w2hi + f);
            half8 bl = *(const half8*)(w2lo + f);
            acc2[nt] = __builtin_amdgcn_mfma_f32_16x16x32_f16(alo2[kt], bh, acc2[nt], 0, 0, 0);
            acc2[nt] = __builtin_amdgcn_mfma_f32_16x16x32_f16(ahi2[kt], bl, acc2[nt], 0, 0, 0);
            acc2[nt] = __builtin_amdgcn_mfma_f32_16x16x32_f16(ahi2[kt], bh, acc2[nt], 0, 0, 0);
        }
    }

    float vv[8][4];
    float sums[4] = {0,0,0,0}, sqs[4] = {0,0,0,0};
#pragma unroll
    for (int nt = 0; nt < 8; ++nt) {
        const int col = nt * 16 + lm;
        const float bias = b2[col];
#pragma unroll
        for (int q = 0; q < 4; ++q) {
            float v2 = acc2[nt][q] + bias;
            vv[nt][q] = v2;
            sums[q] += v2;
            sqs[q]  += v2 * v2;
        }
    }
#pragma unroll
    for (int m = 1; m < 16; m <<= 1) {
#pragma unroll
        for (int q = 0; q < 4; ++q) {
            sums[q] += __shfl_xor(sums[q], m, 64);
            sqs[q]  += __shfl_xor(sqs[q],  m, 64);
        }
    }
    float gam[8], bet[8];
#pragma unroll
    for (int nt = 0; nt < 8; ++nt) {
        gam[nt] = gamma[nt * 16 + lm];
        bet[nt] = beta[nt * 16 + lm];
    }
#pragma unroll
    for (int q = 0; q < 4; ++q) {
        const int grow = r0 + lg * 4 + q;
        if (grow < NN) {
            const float mu  = sums[q] * (1.f / 128.f);
            const float var = sqs[q] * (1.f / 128.f) - mu * mu;
            const float rs  = rsqrtf(var + 1e-5f);
#pragma unroll
            for (int nt = 0; nt < 8; ++nt) {
                const int col = nt * 16 + lm;
                out[(size_t)grow * DD + col] = fmaxf((vv[nt][q] - mu) * rs * gam[nt] + bet[nt], 0.f);
            }
        }
    }
}

extern "C" void kernel_launch(void* const* d_in, const int* in_sizes, int n_in,
                              void* d_out, int out_size, void* d_ws, size_t ws_size,
                              hipStream_t stream) {
    (void)in_sizes; (void)n_in; (void)out_size;
    const float* x     = (const float*)d_in[0];
    const int*   ei    = (const int*)d_in[1];
    const float* ea    = (const float*)d_in[2];
    const float* We    = (const float*)d_in[4];
    const float* be    = (const float*)d_in[5];
    const float* epsp  = (const float*)d_in[6];
    const float* W1    = (const float*)d_in[7];
    const float* b1    = (const float*)d_in[8];
    const float* W2    = (const float*)d_in[9];
    const float* b2    = (const float*)d_in[10];
    const float* gamma = (const float*)d_in[11];
    const float* beta  = (const float*)d_in[12];
    float* out = (float*)d_out;

    // ---- workspace layout (16B-aligned)
    char* ws = (char*)d_ws;
    _Float16* w1hi = (_Float16*)ws;
    _Float16* w1lo = w1hi + DD * DD;
    _Float16* w2hi = w1lo + DD * DD;
    _Float16* w2lo = w2hi + DD * DD;
    size_t off = 4 * (size_t)DD * DD * sizeof(_Float16);       // 131072
    int* counts = (int*)(ws + off);   off += (size_t)NN * 4;
    int* cursor = (int*)(ws + off);   off += (size_t)NN * 4;
    int* start  = (int*)(ws + off);   off += (size_t)NN * 4;
    int* bsum   = (int*)(ws + off);   off += 128 * 4;
    int* boff   = (int*)(ws + off);   off += 128 * 4;
    size_t base2 = off;
    float* rec  = (float*)(ws + off);
    const size_t needA = off + (size_t)EE * 16;                 // ~12.5 MB
    int* sorted_src = (int*)(ws + base2);
    int* sorted_eid = sorted_src + EE;
    const size_t needB = base2 + (size_t)EE * 8;                // ~6.1 MB

    const int NBLK = (NN + 1023) / 1024;

    if (ws_size >= needA) {
        prep_weights<<<(2 * NN + 255) / 256, 256, 0, stream>>>(W1, W2, w1hi, w1lo, w2hi, w2lo, counts);
        hist_kernel<<<(EE + 255) / 256, 256, 0, stream>>>(ei, counts);
        scan_blocks<<<NBLK, 256, 0, stream>>>(counts, start, bsum);
        scan_top<<<1, 128, 0, stream>>>(bsum, boff);
        scatter_rec<<<(EE + 255) / 256, 256, 0, stream>>>(ei, ea, start, boff, cursor, rec);
        agg_rec2<<<(NN * 32 + 255) / 256, 256, 0, stream>>>(x, rec, We, be, start, boff,
                                                            counts, epsp, out);
        node_kernel<true><<<(NN + 63) / 64, 256, 0, stream>>>(x, out, w1hi, w1lo, w2hi, w2lo,
                                                              b1, b2, gamma, beta, epsp, out);
    } else if (ws_size >= needB) {
        prep_weights<<<(2 * NN + 255) / 256, 256, 0, stream>>>(W1, W2, w1hi, w1lo, w2hi, w2lo, counts);
        hist_kernel<<<(EE + 255) / 256, 256, 0, stream>>>(ei, counts);
        scan_blocks<<<NBLK, 256, 0, stream>>>(counts, start, bsum);
        scan_top<<<1, 128, 0, stream>>>(bsum, boff);
        scatter_kernel<<<(EE + 255) / 256, 256, 0, stream>>>(ei, start, boff, cursor,
                                                             sorted_src, sorted_eid);
        agg_kernel<<<(NN * 32 + 255) / 256, 256, 0, stream>>>(x, ea, We, be,
                                                              sorted_src, sorted_eid,
                                                              start, boff, counts, epsp, out);
        node_kernel<true><<<(NN + 63) / 64, 256, 0, stream>>>(x, out, w1hi, w1lo, w2hi, w2lo,
                                                              b1, b2, gamma, beta, epsp, out);
    } else {
        hipMemsetAsync(d_out, 0, (size_t)NN * DD * sizeof(float), stream);
        prep_weights<<<(2 * DD * DD + 255) / 256, 256, 0, stream>>>(W1, W2, w1hi, w1lo, w2hi, w2lo, counts);
        edge_kernel<<<2048, 256, 0, stream>>>(x, ei, ea, We, be, out);
        node_kernel<false><<<(NN + 63) / 64, 256, 0, stream>>>(x, out, w1hi, w1lo, w2hi, w2lo,
                                                               b1, b2, gamma, beta, epsp, out);
    }
}